// Round 1
// baseline (524.767 us; speedup 1.0000x reference)
//
#include <hip/hip_runtime.h>

#define EPS 1e-4f
#define D 64
#define NCASES 8

// ---------------------------------------------------------------------------
// Kernel 1: precompute W_sum (64x64) and b_sum (64) into workspace.
// ws layout: [0..4095] = W_sum (row-major i*64+j), [4096..4159] = b_sum.
// ---------------------------------------------------------------------------
__global__ void prep_sums(const float* __restrict__ W, const float* __restrict__ b,
                          float* __restrict__ ws) {
  int idx = blockIdx.x * blockDim.x + threadIdx.x;
  if (idx < D * D) {
    float s = 0.f;
#pragma unroll
    for (int c = 0; c < NCASES; ++c) s += W[c * D * D + idx];
    ws[idx] = s;
  } else if (idx < D * D + D) {
    int j = idx - D * D;
    float s = 0.f;
#pragma unroll
    for (int c = 0; c < NCASES; ++c) s += b[c * D + j];
    ws[idx] = s;
  }
}

// ---------------------------------------------------------------------------
// Kernel 2: one thread per row.
//   acc[j] = b_sum[j] + sum_i x[i] * W_sum[i][j]        (uniform -> s_load W)
// then (rare, exec-masked) subtract inactive cases:
//   acc[j] -= b_c[j] + sum_i x[i] * W_c[i][j]           for presence<=EPS
// ---------------------------------------------------------------------------
__global__ __launch_bounds__(256, 4) void guarded_layer(
    const float* __restrict__ x, const float* __restrict__ presence,
    const float* __restrict__ W, const float* __restrict__ b,
    const float* __restrict__ Wsum, const float* __restrict__ bsum,
    float* __restrict__ out, int N) {
  int n = blockIdx.x * blockDim.x + threadIdx.x;
  if (n >= N) return;

  const float* xr = x + (size_t)n * D;
  const float4* pr = reinterpret_cast<const float4*>(presence + (size_t)n * NCASES);
  float4 p0 = pr[0];
  float4 p1 = pr[1];
  float pv[NCASES] = {p0.x, p0.y, p0.z, p0.w, p1.x, p1.y, p1.z, p1.w};

  float acc[D];
#pragma unroll
  for (int j = 0; j < D; ++j) acc[j] = bsum[j];

  const float4* xv4 = reinterpret_cast<const float4*>(xr);
  // Outer loop kept rolled (4 iters) so only 16 x-values are live at a time:
  // keeps VGPRs ~<=128 for 4 waves/SIMD, and the 1024-FMA body fits I-cache.
#pragma unroll 1
  for (int i0 = 0; i0 < 4; ++i0) {
    float4 a0 = xv4[i0 * 4 + 0];
    float4 a1 = xv4[i0 * 4 + 1];
    float4 a2 = xv4[i0 * 4 + 2];
    float4 a3 = xv4[i0 * 4 + 3];
    float xs[16] = {a0.x, a0.y, a0.z, a0.w, a1.x, a1.y, a1.z, a1.w,
                    a2.x, a2.y, a2.z, a2.w, a3.x, a3.y, a3.z, a3.w};
#pragma unroll
    for (int ii = 0; ii < 16; ++ii) {
      float xi = xs[ii];
      const float* wr = Wsum + (i0 * 16 + ii) * D;  // uniform address -> s_load
#pragma unroll
      for (int j = 0; j < D; ++j) acc[j] = fmaf(xi, wr[j], acc[j]);
    }
  }

  // Rare path: ~8e-4 of rows have at least one inactive case.
  bool all_active = true;
#pragma unroll
  for (int c = 0; c < NCASES; ++c) all_active = all_active && (pv[c] > EPS);

  if (!all_active) {
#pragma unroll 1
    for (int c = 0; c < NCASES; ++c) {
      if (!(pv[c] > EPS)) {
        const float* bc = b + c * D;
#pragma unroll
        for (int j = 0; j < D; ++j) acc[j] -= bc[j];
        const float* Wc = W + c * D * D;
#pragma unroll 1
        for (int i = 0; i < D; ++i) {
          float xi = xr[i];  // cache-hot reload
          const float* wrow = Wc + i * D;
#pragma unroll
          for (int j = 0; j < D; ++j) acc[j] = fmaf(-xi, wrow[j], acc[j]);
        }
      }
    }
  }

  float4* o = reinterpret_cast<float4*>(out + (size_t)n * D);
#pragma unroll
  for (int q = 0; q < 16; ++q) {
    o[q] = make_float4(acc[4 * q + 0], acc[4 * q + 1], acc[4 * q + 2], acc[4 * q + 3]);
  }
}

extern "C" void kernel_launch(void* const* d_in, const int* in_sizes, int n_in,
                              void* d_out, int out_size, void* d_ws, size_t ws_size,
                              hipStream_t stream) {
  const float* x = (const float*)d_in[0];
  const float* presence = (const float*)d_in[1];
  const float* W = (const float*)d_in[2];
  const float* b = (const float*)d_in[3];
  float* out = (float*)d_out;
  float* ws = (float*)d_ws;

  int N = in_sizes[0] / D;

  // 4096 W_sum elements + 64 b_sum elements
  prep_sums<<<(D * D + D + 255) / 256, 256, 0, stream>>>(W, b, ws);

  guarded_layer<<<(N + 255) / 256, 256, 0, stream>>>(
      x, presence, W, b, ws, ws + D * D, out, N);
}